// Round 1
// baseline (1086.836 us; speedup 1.0000x reference)
//
#include <hip/hip_runtime.h>
#include <math.h>

// Problem constants
#define BB 2
#define NN 512
#define CS 384
#define CP 128
#define CH 16
#define HH 12
#define PQN 4
#define PVN 8
#define COUT 2112   // H*CH + 4*H*PV + H*CP = 192+384+1536

#define QK_SCALE 0.14433756729740643f   // 1/sqrt(3*16)
#define BB_SCALE 0.57735026918962576f   // 1/sqrt(3)
#define HW_COEF  0.13608276348795434f   // 1/sqrt(3*(4*9/2)) = 1/sqrt(54)

// ---------------------------------------------------------------------------
// K1: projections  s @ {wq, wkv, wq_pts, wkv_pts}  with layout scatter.
// Block = 8 rows, 256 threads. 1152 total output columns.
// ---------------------------------------------------------------------------
__global__ __launch_bounds__(256) void k_proj(
    const float* __restrict__ s,
    const float* __restrict__ wq,  const float* __restrict__ bq,
    const float* __restrict__ wkv, const float* __restrict__ bkv,
    const float* __restrict__ wqp, const float* __restrict__ bqp,
    const float* __restrict__ wkvp,const float* __restrict__ bkvp,
    float* __restrict__ q_o,    // (B,N,192)
    float* __restrict__ kT,     // (B,12,16,512)
    float* __restrict__ vT,     // (B,12,16,512)
    float* __restrict__ qpl,    // (B,N,H,PQ,3) local frame
    float* __restrict__ kvpl)   // (B,N,H,12,3) local frame
{
    __shared__ __align__(16) float s_lds[8 * CS];
    const int row0 = blockIdx.x * 8;
    const int t = threadIdx.x;
    for (int idx = t; idx < 8 * CS; idx += 256) s_lds[idx] = s[(size_t)row0 * CS + idx];
    __syncthreads();

    for (int col = t; col < 1152; col += 256) {
        const float* w; int sub, wcols; float bias;
        if (col < 192)      { w = wq;   sub = col;       wcols = 192; bias = bq[sub]; }
        else if (col < 576) { w = wkv;  sub = col - 192; wcols = 384; bias = bkv[sub]; }
        else if (col < 720) { w = wqp;  sub = col - 576; wcols = 144; bias = bqp[sub]; }
        else                { w = wkvp; sub = col - 720; wcols = 432; bias = bkvp[sub]; }
        float acc[8];
        #pragma unroll
        for (int r = 0; r < 8; ++r) acc[r] = bias;
        for (int k = 0; k < CS; k += 4) {
            float w0 = w[(k + 0) * wcols + sub];
            float w1 = w[(k + 1) * wcols + sub];
            float w2 = w[(k + 2) * wcols + sub];
            float w3 = w[(k + 3) * wcols + sub];
            #pragma unroll
            for (int r = 0; r < 8; ++r) {
                float4 sv = *(const float4*)&s_lds[r * CS + k];
                acc[r] += sv.x * w0 + sv.y * w1 + sv.z * w2 + sv.w * w3;
            }
        }
        #pragma unroll
        for (int r = 0; r < 8; ++r) {
            int row = row0 + r;
            int b = row >> 9, n = row & 511;
            float v = acc[r];
            if (col < 192) {
                q_o[(size_t)row * 192 + sub] = v;
            } else if (col < 576) {
                int h = sub >> 5, rr = sub & 31;
                if (rr < 16) kT[(((b * 12 + h) * 16 + rr) << 9) + n] = v;
                else         vT[(((b * 12 + h) * 16 + (rr - 16)) << 9) + n] = v;
            } else if (col < 720) {
                int axis = sub / 48, rem = sub % 48;      // rem = h*4+pt
                qpl[(size_t)row * 144 + rem * 3 + axis] = v;
            } else {
                int axis = sub / 144, rem = sub % 144;    // rem = h*12+pt
                kvpl[(size_t)row * 432 + rem * 3 + axis] = v;
            }
        }
    }
}

// ---------------------------------------------------------------------------
// K2: local->global point transform + transposed scatter for k_pts / v_pts
// grid = B*N blocks, 192 threads (one per point)
// ---------------------------------------------------------------------------
__global__ __launch_bounds__(192) void k_pts(
    const float* __restrict__ qpl, const float* __restrict__ kvpl,
    const float* __restrict__ t_rot, const float* __restrict__ t_trans,
    float* __restrict__ qpg,    // (B,N,H,PQ,3) global
    float* __restrict__ kptsT,  // (B,12,12,512)
    float* __restrict__ vptsT)  // (B,12,24,512)
{
    const int row = blockIdx.x;
    const int b = row >> 9, n = row & 511;
    const int t = threadIdx.x;
    __shared__ float R[9], T[3];
    if (t < 9) R[t] = t_rot[(size_t)row * 9 + t];
    if (t < 3) T[t] = t_trans[(size_t)row * 3 + t];
    __syncthreads();
    float lx, ly, lz;
    if (t < 48) {
        lx = qpl[(size_t)row * 144 + t * 3 + 0];
        ly = qpl[(size_t)row * 144 + t * 3 + 1];
        lz = qpl[(size_t)row * 144 + t * 3 + 2];
    } else {
        int pp = t - 48;
        lx = kvpl[(size_t)row * 432 + pp * 3 + 0];
        ly = kvpl[(size_t)row * 432 + pp * 3 + 1];
        lz = kvpl[(size_t)row * 432 + pp * 3 + 2];
    }
    float gx = R[0] * lx + R[1] * ly + R[2] * lz + T[0];
    float gy = R[3] * lx + R[4] * ly + R[5] * lz + T[1];
    float gz = R[6] * lx + R[7] * ly + R[8] * lz + T[2];
    if (t < 48) {
        qpg[(size_t)row * 144 + t * 3 + 0] = gx;
        qpg[(size_t)row * 144 + t * 3 + 1] = gy;
        qpg[(size_t)row * 144 + t * 3 + 2] = gz;
    } else {
        int pp = t - 48;
        int h = pp / 12, pt = pp % 12;
        if (pt < 4) {
            int base = (((b * 12 + h) * 12 + pt * 3) << 9) + n;
            kptsT[base] = gx; kptsT[base + 512] = gy; kptsT[base + 1024] = gz;
        } else {
            int base = (((b * 12 + h) * 24 + (pt - 4) * 3) << 9) + n;
            vptsT[base] = gx; vptsT[base + 512] = gy; vptsT[base + 1024] = gz;
        }
    }
}

// ---------------------------------------------------------------------------
// K3: attention mega-kernel. One block per (b, i) row, 256 threads.
// LDS: logits [12][512], p tile [32][132], wb [128*12], small staging. ~50 KB.
// ---------------------------------------------------------------------------
#define SM_L    0        // 6144   logits [12][512]
#define SM_PT   6144     // 4224   p tile [32][132]
#define SM_WB   10368    // 1536
#define SM_Q    11904    // 192
#define SM_QP   12096    // 144
#define SM_OPT  12240    // 288
#define SM_R    12528    // 9
#define SM_T    12537    // 3
#define SM_HW   12540    // 12
#define SM_MI   12552    // 1
#define SM_TOT  12560

__global__ __launch_bounds__(256) void k_attn(
    const float* __restrict__ q_o,   // (B,N,192)
    const float* __restrict__ kT,    // (B,12,16,512)
    const float* __restrict__ vT,    // (B,12,16,512)
    const float* __restrict__ qpg,   // (B,N,144)
    const float* __restrict__ kptsT, // (B,12,12,512)
    const float* __restrict__ vptsT, // (B,12,24,512)
    const float* __restrict__ p,     // (B,N,N,128)
    const float* __restrict__ wb,    // (128,12)
    const float* __restrict__ bpb,   // (12)
    const float* __restrict__ hwts,  // (12)
    const float* __restrict__ mask,  // (B,N)
    const float* __restrict__ t_rot, const float* __restrict__ t_trans,
    float* __restrict__ feats)       // (B,N,2112)
{
    __shared__ __align__(16) float smem[SM_TOT];
    float* l_s    = smem + SM_L;
    float* p_tile = smem + SM_PT;
    float* wb_s   = smem + SM_WB;
    float* q_s    = smem + SM_Q;
    float* qp_s   = smem + SM_QP;
    float* optg_s = smem + SM_OPT;
    float* R_s    = smem + SM_R;
    float* T_s    = smem + SM_T;
    float* hw_s   = smem + SM_HW;

    const int row = blockIdx.x;
    const int b = row >> 9, i = row & 511;
    const int t = threadIdx.x;

    // phase 0: stage per-row data
    for (int idx = t; idx < 192; idx += 256)  q_s[idx] = q_o[(size_t)row * 192 + idx];
    for (int idx = t; idx < 144; idx += 256)  qp_s[idx] = qpg[(size_t)row * 144 + idx];
    for (int idx = t; idx < 1536; idx += 256) wb_s[idx] = wb[idx];
    if (t < 12) {
        float x = hwts[t];
        float sp = (x > 20.f) ? x : log1pf(__expf(x));
        hw_s[t] = sp * HW_COEF;
    }
    if (t < 9) R_s[t] = t_rot[(size_t)row * 9 + t];
    if (t < 3) T_s[t] = t_trans[(size_t)row * 3 + t];
    if (t == 0) smem[SM_MI] = mask[row];
    __syncthreads();
    const float mi = smem[SM_MI];

    // phase 1: logits = qk*scale + pt_att + bpb term + mask term
    for (int jr = 0; jr < 2; ++jr) {
        int j = t + jr * 256;
        float mj = mask[b * 512 + j];
        float maskterm = 100000.0f * (mi * mj - 1.0f);
        for (int h = 0; h < 12; ++h) {
            const float* kh = kT + ((size_t)((b * 12 + h) * 16) << 9) + j;
            float qk = 0.f;
            #pragma unroll
            for (int c = 0; c < 16; ++c) qk += q_s[h * 16 + c] * kh[c << 9];
            const float* kp = kptsT + ((size_t)((b * 12 + h) * 12) << 9) + j;
            float d2 = 0.f;
            #pragma unroll
            for (int px = 0; px < 12; ++px) {
                float d = qp_s[h * 12 + px] - kp[px << 9];
                d2 += d * d;
            }
            l_s[h * 512 + j] = QK_SCALE * qk - 0.5f * hw_s[h] * d2
                               + BB_SCALE * bpb[h] + maskterm;
        }
    }
    __syncthreads();

    // phase 2: logits += BB_SCALE * (p @ wb) ; p staged in 32-row tiles
    {
        const int jj = t & 31, cq = t >> 5;     // cq: 8-way split over c
        const int c0 = cq * 16;
        for (int tile = 0; tile < 16; ++tile) {
            int j0 = tile * 32;
            __syncthreads();
            const float* psrc = p + (((size_t)(b * 512 + i)) * 512 + j0) * 128;
            for (int idx = t; idx < 32 * 128; idx += 256) {
                int r2 = idx >> 7, c2 = idx & 127;
                p_tile[r2 * 132 + c2] = psrc[idx];
            }
            __syncthreads();
            float partial[12];
            #pragma unroll
            for (int h = 0; h < 12; ++h) partial[h] = 0.f;
            #pragma unroll
            for (int c4 = 0; c4 < 4; ++c4) {
                float4 pv = *(const float4*)&p_tile[jj * 132 + c0 + c4 * 4];
                float pvals[4] = {pv.x, pv.y, pv.z, pv.w};
                #pragma unroll
                for (int u = 0; u < 4; ++u) {
                    float pu = pvals[u];
                    int c = c0 + c4 * 4 + u;
                    float4 w0 = *(const float4*)&wb_s[c * 12 + 0];
                    float4 w1 = *(const float4*)&wb_s[c * 12 + 4];
                    float4 w2 = *(const float4*)&wb_s[c * 12 + 8];
                    partial[0] += pu * w0.x; partial[1] += pu * w0.y;
                    partial[2] += pu * w0.z; partial[3] += pu * w0.w;
                    partial[4] += pu * w1.x; partial[5] += pu * w1.y;
                    partial[6] += pu * w1.z; partial[7] += pu * w1.w;
                    partial[8] += pu * w2.x; partial[9] += pu * w2.y;
                    partial[10] += pu * w2.z; partial[11] += pu * w2.w;
                }
            }
            __syncthreads();
            float* red = p_tile;   // overlay: [8 cq][32 jj][12 h]
            #pragma unroll
            for (int h = 0; h < 12; ++h) red[t * 12 + h] = partial[h];
            __syncthreads();
            for (int idx = t; idx < 384; idx += 256) {
                int j2 = idx / 12, h2 = idx % 12;
                float sum = 0.f;
                #pragma unroll
                for (int cq2 = 0; cq2 < 8; ++cq2) sum += red[(cq2 * 32 + j2) * 12 + h2];
                l_s[h2 * 512 + j0 + j2] += BB_SCALE * sum;
            }
        }
        __syncthreads();
    }

    // phase 3: softmax per (head) row; wave w handles heads 3w..3w+2
    {
        const int w = t >> 6, lane = t & 63;
        for (int h = w * 3; h < w * 3 + 3; ++h) {
            float m = -1e30f;
            for (int j = lane; j < 512; j += 64) m = fmaxf(m, l_s[h * 512 + j]);
            #pragma unroll
            for (int o = 32; o > 0; o >>= 1) m = fmaxf(m, __shfl_xor(m, o, 64));
            float ssum = 0.f;
            for (int j = lane; j < 512; j += 64) {
                float e = __expf(l_s[h * 512 + j] - m);
                l_s[h * 512 + j] = e;
                ssum += e;
            }
            #pragma unroll
            for (int o = 32; o > 0; o >>= 1) ssum += __shfl_xor(ssum, o, 64);
            float inv = 1.0f / ssum;
            for (int j = lane; j < 512; j += 64) l_s[h * 512 + j] *= inv;
        }
    }
    __syncthreads();

    // phase 4: o = a@v (192 outs) and o_pt_g = a@v_pts (288 outs), wave-per-output
    {
        const int w = t >> 6, lane = t & 63;
        for (int oi = w; oi < 480; oi += 4) {
            const float* src; int h;
            if (oi < 192) { h = oi >> 4; src = vT + ((size_t)((b * 12 + h) * 16 + (oi & 15)) << 9); }
            else { int o2 = oi - 192; h = o2 / 24; src = vptsT + ((size_t)((b * 12 + h) * 24 + (o2 % 24)) << 9); }
            float acc = 0.f;
            for (int j = lane; j < 512; j += 64) acc += l_s[h * 512 + j] * src[j];
            #pragma unroll
            for (int o = 32; o > 0; o >>= 1) acc += __shfl_xor(acc, o, 64);
            if (lane == 0) {
                if (oi < 192) feats[(size_t)row * 2112 + oi] = acc;
                else          optg_s[oi - 192] = acc;
            }
        }
    }
    __syncthreads();

    // epilogue: o_pt = R^T (o_pt_g - t), norms, scatter into feats
    if (t < 96) {
        float gx = optg_s[t * 3 + 0] - T_s[0];
        float gy = optg_s[t * 3 + 1] - T_s[1];
        float gz = optg_s[t * 3 + 2] - T_s[2];
        float ox = R_s[0] * gx + R_s[3] * gy + R_s[6] * gz;
        float oy = R_s[1] * gx + R_s[4] * gy + R_s[7] * gz;
        float oz = R_s[2] * gx + R_s[5] * gy + R_s[8] * gz;
        float nrm = sqrtf(ox * ox + oy * oy + oz * oz + 1e-8f);
        size_t fb = (size_t)row * 2112;
        feats[fb + 192 + t] = ox;
        feats[fb + 288 + t] = oy;
        feats[fb + 384 + t] = oz;
        feats[fb + 480 + t] = nrm;
    }

    // phase 5: o_pair[h][c] = sum_j a[h][j] * p[i][j][c]
    {
        const int cg = t & 31, js = t >> 5;
        const int c0 = cg * 4;
        float acc[12][4];
        #pragma unroll
        for (int h = 0; h < 12; ++h) {
            #pragma unroll
            for (int u = 0; u < 4; ++u) acc[h][u] = 0.f;
        }
        for (int tile = 0; tile < 16; ++tile) {
            int j0 = tile * 32;
            __syncthreads();
            const float* psrc = p + (((size_t)(b * 512 + i)) * 512 + j0) * 128;
            for (int idx = t; idx < 32 * 128; idx += 256) {
                int r2 = idx >> 7, c2 = idx & 127;
                p_tile[r2 * 132 + c2] = psrc[idx];
            }
            __syncthreads();
            #pragma unroll
            for (int jjl = 0; jjl < 4; ++jjl) {
                int jj = js * 4 + jjl;
                float4 pv = *(const float4*)&p_tile[jj * 132 + c0];
                #pragma unroll
                for (int h = 0; h < 12; ++h) {
                    float lv = l_s[h * 512 + j0 + jj];
                    acc[h][0] += lv * pv.x; acc[h][1] += lv * pv.y;
                    acc[h][2] += lv * pv.z; acc[h][3] += lv * pv.w;
                }
            }
        }
        __syncthreads();
        float* red2 = smem;   // overlay everything: [256 t][48]
        #pragma unroll
        for (int h = 0; h < 12; ++h) {
            #pragma unroll
            for (int u = 0; u < 4; ++u) red2[t * 48 + h * 4 + u] = acc[h][u];
        }
        __syncthreads();
        size_t fb = (size_t)row * 2112 + 576;
        for (int o = t; o < 1536; o += 256) {
            int h = o >> 7, c = o & 127, cg2 = c >> 2, u = c & 3;
            float sum = 0.f;
            #pragma unroll
            for (int js2 = 0; js2 < 8; ++js2) sum += red2[(js2 * 32 + cg2) * 48 + h * 4 + u];
            feats[fb + o] = sum;
        }
    }
}

// ---------------------------------------------------------------------------
// K4: row-panel GEMM: out = f(A @ W + bias [+resid]) with optional relu / LN.
// Block = 4 rows x 384 cols, 384 threads. grid = 256.
// ---------------------------------------------------------------------------
__global__ __launch_bounds__(384) void k_rowgemm(
    const float* __restrict__ A, const float* __restrict__ W,
    const float* __restrict__ bias,
    const float* __restrict__ resid,   // nullable
    const float* __restrict__ gamma, const float* __restrict__ beta, // nullable -> LN
    float* __restrict__ out, int K, int do_relu)
{
    __shared__ __align__(16) float a_s[4 * 2112];
    __shared__ float red_s[4][12];
    __shared__ float mv_s[4][2];
    const int row0 = blockIdx.x * 4;
    const int t = threadIdx.x;  // 0..383 = output column
    for (int idx = t; idx < 4 * K; idx += 384) a_s[idx] = A[(size_t)row0 * K + idx];
    __syncthreads();
    float acc[4] = {0.f, 0.f, 0.f, 0.f};
    for (int k = 0; k < K; k += 4) {
        float w0 = W[(size_t)(k + 0) * 384 + t];
        float w1 = W[(size_t)(k + 1) * 384 + t];
        float w2 = W[(size_t)(k + 2) * 384 + t];
        float w3 = W[(size_t)(k + 3) * 384 + t];
        #pragma unroll
        for (int r = 0; r < 4; ++r) {
            float4 av = *(const float4*)&a_s[r * K + k];
            acc[r] += av.x * w0 + av.y * w1 + av.z * w2 + av.w * w3;
        }
    }
    float bv = bias[t];
    #pragma unroll
    for (int r = 0; r < 4; ++r) {
        acc[r] += bv;
        if (do_relu) acc[r] = fmaxf(acc[r], 0.f);
        if (resid) acc[r] += resid[(size_t)(row0 + r) * 384 + t];
    }
    if (gamma) {
        const int w = t >> 6, lane = t & 63;
        #pragma unroll
        for (int r = 0; r < 4; ++r) {
            float sv = acc[r], sq = acc[r] * acc[r];
            #pragma unroll
            for (int o = 32; o > 0; o >>= 1) {
                sv += __shfl_xor(sv, o, 64);
                sq += __shfl_xor(sq, o, 64);
            }
            if (lane == 0) { red_s[r][w * 2 + 0] = sv; red_s[r][w * 2 + 1] = sq; }
        }
        __syncthreads();
        if (t < 4) {
            float sv = 0.f, sq = 0.f;
            for (int w2 = 0; w2 < 6; ++w2) { sv += red_s[t][w2 * 2]; sq += red_s[t][w2 * 2 + 1]; }
            float mean = sv / 384.f;
            float var = sq / 384.f - mean * mean;
            mv_s[t][0] = mean; mv_s[t][1] = rsqrtf(var + 1e-5f);
        }
        __syncthreads();
        #pragma unroll
        for (int r = 0; r < 4; ++r)
            acc[r] = (acc[r] - mv_s[r][0]) * mv_s[r][1] * gamma[t] + beta[t];
    }
    #pragma unroll
    for (int r = 0; r < 4; ++r) out[(size_t)(row0 + r) * 384 + t] = acc[r];
}

// ---------------------------------------------------------------------------
// K5: backbone update. One wave per row (1024 rows). grid 256 x 256 threads.
// ---------------------------------------------------------------------------
__global__ __launch_bounds__(256) void k_bb(
    const float* __restrict__ sfin, const float* __restrict__ w_bb,
    const float* __restrict__ b_bb,
    const float* __restrict__ t_rot, const float* __restrict__ t_trans,
    float* __restrict__ rot_out, float* __restrict__ trans_out)
{
    const int wid = (blockIdx.x * 256 + threadIdx.x) >> 6;  // row
    const int lane = threadIdx.x & 63;
    const float* srow = sfin + (size_t)wid * 384;
    float u[6] = {0.f, 0.f, 0.f, 0.f, 0.f, 0.f};
    for (int k = lane; k < 384; k += 64) {
        float sv = srow[k];
        #pragma unroll
        for (int j = 0; j < 6; ++j) u[j] += sv * w_bb[k * 6 + j];
    }
    #pragma unroll
    for (int j = 0; j < 6; ++j) {
        #pragma unroll
        for (int o = 32; o > 0; o >>= 1) u[j] += __shfl_xor(u[j], o, 64);
    }
    if (lane == 0) {
        #pragma unroll
        for (int j = 0; j < 6; ++j) u[j] += b_bb[j];
        float bq = u[0], cq = u[1], dq = u[2];
        float inv = rsqrtf(1.f + bq * bq + cq * cq + dq * dq);
        float a = inv, bqn = bq * inv, cqn = cq * inv, dqn = dq * inv;
        float R[9];
        R[0] = a * a + bqn * bqn - cqn * cqn - dqn * dqn;
        R[1] = 2.f * (bqn * cqn - a * dqn);
        R[2] = 2.f * (bqn * dqn + a * cqn);
        R[3] = 2.f * (bqn * cqn + a * dqn);
        R[4] = a * a - bqn * bqn + cqn * cqn - dqn * dqn;
        R[5] = 2.f * (cqn * dqn - a * bqn);
        R[6] = 2.f * (bqn * dqn - a * cqn);
        R[7] = 2.f * (cqn * dqn + a * bqn);
        R[8] = a * a - bqn * bqn - cqn * cqn + dqn * dqn;
        const float* Rt = t_rot + (size_t)wid * 9;
        #pragma unroll
        for (int i2 = 0; i2 < 3; ++i2) {
            #pragma unroll
            for (int k2 = 0; k2 < 3; ++k2) {
                rot_out[(size_t)wid * 9 + i2 * 3 + k2] =
                    Rt[i2 * 3 + 0] * R[0 + k2] + Rt[i2 * 3 + 1] * R[3 + k2] + Rt[i2 * 3 + 2] * R[6 + k2];
            }
            trans_out[(size_t)wid * 3 + i2] =
                Rt[i2 * 3 + 0] * u[3] + Rt[i2 * 3 + 1] * u[4] + Rt[i2 * 3 + 2] * u[5]
                + t_trans[(size_t)wid * 3 + i2];
        }
    }
}

// ---------------------------------------------------------------------------
extern "C" void kernel_launch(void* const* d_in, const int* in_sizes, int n_in,
                              void* d_out, int out_size, void* d_ws, size_t ws_size,
                              hipStream_t stream) {
    const float* s      = (const float*)d_in[0];
    const float* p      = (const float*)d_in[1];
    const float* t_rot  = (const float*)d_in[2];
    const float* t_trans= (const float*)d_in[3];
    const float* mask   = (const float*)d_in[4];
    const float* wq     = (const float*)d_in[5];
    const float* bq     = (const float*)d_in[6];
    const float* wkv    = (const float*)d_in[7];
    const float* bkv    = (const float*)d_in[8];
    const float* wqp    = (const float*)d_in[9];
    const float* bqp    = (const float*)d_in[10];
    const float* wkvp   = (const float*)d_in[11];
    const float* bkvp   = (const float*)d_in[12];
    const float* wb     = (const float*)d_in[13];
    const float* bpb    = (const float*)d_in[14];
    const float* hwts   = (const float*)d_in[15];
    const float* w_out  = (const float*)d_in[16];
    const float* b_out  = (const float*)d_in[17];
    const float* ln1s   = (const float*)d_in[18];
    const float* ln1b   = (const float*)d_in[19];
    const float* wt1    = (const float*)d_in[20];
    const float* bt1    = (const float*)d_in[21];
    const float* wt2    = (const float*)d_in[22];
    const float* bt2    = (const float*)d_in[23];
    const float* wt3    = (const float*)d_in[24];
    const float* bt3    = (const float*)d_in[25];
    const float* ln2s   = (const float*)d_in[26];
    const float* ln2b   = (const float*)d_in[27];
    const float* w_bb   = (const float*)d_in[28];
    const float* b_bb   = (const float*)d_in[29];
    float* out = (float*)d_out;
    float* ws  = (float*)d_ws;

    float* q_o   = ws;                  // 196608
    float* kT    = q_o + 196608;        // 196608
    float* vT    = kT + 196608;         // 196608
    float* qpl   = vT + 196608;         // 147456
    float* qpg   = qpl + 147456;        // 147456
    float* kvpl  = qpg + 147456;        // 442368
    float* kptsT = kvpl + 442368;       // 147456
    float* vptsT = kptsT + 147456;      // 294912
    float* feats = vptsT + 294912;      // 2162688
    float* s1    = feats + 2162688;     // 393216
    float* h1    = s1 + 393216;         // 393216
    float* h2    = h1 + 393216;         // 393216

    k_proj<<<128, 256, 0, stream>>>(s, wq, bq, wkv, bkv, wqp, bqp, wkvp, bkvp,
                                    q_o, kT, vT, qpl, kvpl);
    k_pts<<<1024, 192, 0, stream>>>(qpl, kvpl, t_rot, t_trans, qpg, kptsT, vptsT);
    k_attn<<<1024, 256, 0, stream>>>(q_o, kT, vT, qpg, kptsT, vptsT, p, wb, bpb,
                                     hwts, mask, t_rot, t_trans, feats);
    k_rowgemm<<<256, 384, 0, stream>>>(feats, w_out, b_out, s, ln1s, ln1b, s1, 2112, 0);
    k_rowgemm<<<256, 384, 0, stream>>>(s1, wt1, bt1, nullptr, nullptr, nullptr, h1, 384, 1);
    k_rowgemm<<<256, 384, 0, stream>>>(h1, wt2, bt2, nullptr, nullptr, nullptr, h2, 384, 1);
    k_rowgemm<<<256, 384, 0, stream>>>(h2, wt3, bt3, s1, ln2s, ln2b, out, 384, 0);
    k_bb<<<256, 256, 0, stream>>>(out, w_bb, b_bb, t_rot, t_trans,
                                  out + 393216, out + 402432);
}

// Round 2
// 656.904 us; speedup vs baseline: 1.6545x; 1.6545x over previous
//
#include <hip/hip_runtime.h>
#include <math.h>

// Problem constants
#define CS 384
#define QK_SCALE 0.14433756729740643f   // 1/sqrt(3*16)
#define BB_SCALE 0.57735026918962576f   // 1/sqrt(3)
#define HW_COEF  0.13608276348795434f   // 1/sqrt(54)

// ---------------------------------------------------------------------------
// K1: projections  s @ {wq, wkv, wq_pts, wkv_pts}  with layout scatter.
// Block = 4 rows x 288-col group, 256 threads. grid = 256 rowblks * 4 colgrps.
// ---------------------------------------------------------------------------
__global__ __launch_bounds__(256) void k_proj(
    const float* __restrict__ s,
    const float* __restrict__ wq,  const float* __restrict__ bq,
    const float* __restrict__ wkv, const float* __restrict__ bkv,
    const float* __restrict__ wqp, const float* __restrict__ bqp,
    const float* __restrict__ wkvp,const float* __restrict__ bkvp,
    float* __restrict__ q_o,    // (B,N,192)
    float* __restrict__ kT,     // (B,12,16,512)
    float* __restrict__ vT,     // (B,12,16,512)
    float* __restrict__ qpl,    // (B,N,H,PQ,3) local frame
    float* __restrict__ kvpl)   // (B,N,H,12,3) local frame
{
    __shared__ __align__(16) float s_lds[4 * CS];
    const int rowblk = blockIdx.x >> 2, cgp = blockIdx.x & 3;
    const int row0 = rowblk * 4;
    const int t = threadIdx.x;
    for (int idx = t; idx < 4 * CS; idx += 256) s_lds[idx] = s[(size_t)row0 * CS + idx];
    __syncthreads();

    for (int col = cgp * 288 + t; col < cgp * 288 + 288; col += 256) {
        const float* w; int sub, wcols; float bias;
        if (col < 192)      { w = wq;   sub = col;       wcols = 192; bias = bq[sub]; }
        else if (col < 576) { w = wkv;  sub = col - 192; wcols = 384; bias = bkv[sub]; }
        else if (col < 720) { w = wqp;  sub = col - 576; wcols = 144; bias = bqp[sub]; }
        else                { w = wkvp; sub = col - 720; wcols = 432; bias = bkvp[sub]; }
        float acc[4];
        #pragma unroll
        for (int r = 0; r < 4; ++r) acc[r] = bias;
        for (int k = 0; k < CS; k += 4) {
            float w0 = w[(size_t)(k + 0) * wcols + sub];
            float w1 = w[(size_t)(k + 1) * wcols + sub];
            float w2 = w[(size_t)(k + 2) * wcols + sub];
            float w3 = w[(size_t)(k + 3) * wcols + sub];
            #pragma unroll
            for (int r = 0; r < 4; ++r) {
                float4 sv = *(const float4*)&s_lds[r * CS + k];
                acc[r] += sv.x * w0 + sv.y * w1 + sv.z * w2 + sv.w * w3;
            }
        }
        #pragma unroll
        for (int r = 0; r < 4; ++r) {
            int row = row0 + r;
            int b = row >> 9, n = row & 511;
            float v = acc[r];
            if (col < 192) {
                q_o[(size_t)row * 192 + sub] = v;
            } else if (col < 576) {
                int h = sub >> 5, rr = sub & 31;
                if (rr < 16) kT[(((b * 12 + h) * 16 + rr) << 9) + n] = v;
                else         vT[(((b * 12 + h) * 16 + (rr - 16)) << 9) + n] = v;
            } else if (col < 720) {
                int axis = sub / 48, rem = sub % 48;      // rem = h*4+pt
                qpl[(size_t)row * 144 + rem * 3 + axis] = v;
            } else {
                int axis = sub / 144, rem = sub % 144;    // rem = h*12+pt
                kvpl[(size_t)row * 432 + rem * 3 + axis] = v;
            }
        }
    }
}

// ---------------------------------------------------------------------------
// K2: local->global point transform + transposed scatter for k_pts / v_pts
// ---------------------------------------------------------------------------
__global__ __launch_bounds__(192) void k_pts(
    const float* __restrict__ qpl, const float* __restrict__ kvpl,
    const float* __restrict__ t_rot, const float* __restrict__ t_trans,
    float* __restrict__ qpg,    // (B,N,H,PQ,3) global
    float* __restrict__ kptsT,  // (B,12,12,512)
    float* __restrict__ vptsT)  // (B,12,24,512)
{
    const int row = blockIdx.x;
    const int b = row >> 9, n = row & 511;
    const int t = threadIdx.x;
    __shared__ float R[9], T[3];
    if (t < 9) R[t] = t_rot[(size_t)row * 9 + t];
    if (t < 3) T[t] = t_trans[(size_t)row * 3 + t];
    __syncthreads();
    float lx, ly, lz;
    if (t < 48) {
        lx = qpl[(size_t)row * 144 + t * 3 + 0];
        ly = qpl[(size_t)row * 144 + t * 3 + 1];
        lz = qpl[(size_t)row * 144 + t * 3 + 2];
    } else {
        int pp = t - 48;
        lx = kvpl[(size_t)row * 432 + pp * 3 + 0];
        ly = kvpl[(size_t)row * 432 + pp * 3 + 1];
        lz = kvpl[(size_t)row * 432 + pp * 3 + 2];
    }
    float gx = R[0] * lx + R[1] * ly + R[2] * lz + T[0];
    float gy = R[3] * lx + R[4] * ly + R[5] * lz + T[1];
    float gz = R[6] * lx + R[7] * ly + R[8] * lz + T[2];
    if (t < 48) {
        qpg[(size_t)row * 144 + t * 3 + 0] = gx;
        qpg[(size_t)row * 144 + t * 3 + 1] = gy;
        qpg[(size_t)row * 144 + t * 3 + 2] = gz;
    } else {
        int pp = t - 48;
        int h = pp / 12, pt = pp % 12;
        if (pt < 4) {
            int base = (((b * 12 + h) * 12 + pt * 3) << 9) + n;
            kptsT[base] = gx; kptsT[base + 512] = gy; kptsT[base + 1024] = gz;
        } else {
            int base = (((b * 12 + h) * 24 + (pt - 4) * 3) << 9) + n;
            vptsT[base] = gx; vptsT[base + 512] = gy; vptsT[base + 1024] = gz;
        }
    }
}

// ---------------------------------------------------------------------------
// K3: attention mega-kernel. One block per (b, i) row, 256 threads.
// region0 = smem[0..6144)   : l_s [12][512]   (later red2 overlay with region1)
// region1 = smem[6144..12288): wb_s(1536) + p_tile(32*132=4224)  -> a_t (6144)
// ---------------------------------------------------------------------------
__global__ __launch_bounds__(256) void k_attn(
    const float* __restrict__ q_o,   // (B,N,192)
    const float* __restrict__ kT,    // (B,12,16,512)
    const float* __restrict__ vT,    // (B,12,16,512)
    const float* __restrict__ qpg,   // (B,N,144)
    const float* __restrict__ kptsT, // (B,12,12,512)
    const float* __restrict__ vptsT, // (B,12,24,512)
    const float* __restrict__ p,     // (B,N,N,128)
    const float* __restrict__ wb,    // (128,12)
    const float* __restrict__ bpb,   // (12)
    const float* __restrict__ hwts,  // (12)
    const float* __restrict__ mask,  // (B,N)
    const float* __restrict__ t_rot, const float* __restrict__ t_trans,
    float* __restrict__ feats)       // (B,N,2112)
{
    __shared__ __align__(16) float smem[12288];
    __shared__ __align__(16) float q_s[192];
    __shared__ __align__(16) float qp_s[144];
    __shared__ __align__(16) float optg_s[288];
    __shared__ float R_s[9], T_s[3], hw_s[12], misc_s[4];

    float* l_s    = smem;            // [12][512]
    float* wb_s   = smem + 6144;     // [128][12]   (phases 0-2)
    float* p_tile = smem + 7680;     // [32][132]   (phase 2)
    float* red    = p_tile;          // [256][12]   (phase 2 reduction)
    float* a_t    = smem + 6144;     // [512][12]   (phases 3+)
    float* red2   = smem;            // [48][256]   (phase 5 reduction)

    const int row = blockIdx.x;
    const int b = row >> 9, i = row & 511;
    const int t = threadIdx.x;
    const float* psrc = p + ((size_t)(b * 512 + i) * 512) * 128;

    // phase 0: stage per-row data
    for (int idx = t; idx < 192; idx += 256)  q_s[idx] = q_o[(size_t)row * 192 + idx];
    for (int idx = t; idx < 144; idx += 256)  qp_s[idx] = qpg[(size_t)row * 144 + idx];
    for (int idx = t; idx < 1536; idx += 256) wb_s[idx] = wb[idx];
    if (t < 12) {
        float x = hwts[t];
        float sp = (x > 20.f) ? x : log1pf(__expf(x));
        hw_s[t] = sp * HW_COEF;
    }
    if (t < 9) R_s[t] = t_rot[(size_t)row * 9 + t];
    if (t < 3) T_s[t] = t_trans[(size_t)row * 3 + t];
    if (t == 0) misc_s[0] = mask[row];
    __syncthreads();
    const float mi = misc_s[0];

    // issue prefetch of p tile 0 (latency hides under phase 1)
    float4 pre[4];
    #pragma unroll
    for (int u = 0; u < 4; ++u) {
        int q = u * 256 + t;
        pre[u] = *(const float4*)&psrc[(size_t)(q >> 5) * 128 + (q & 31) * 4];
    }

    // phase 1: logits = qk*scale + pt_att + bpb + mask
    for (int jr = 0; jr < 2; ++jr) {
        int j = t + jr * 256;
        float mj = mask[b * 512 + j];
        float maskterm = 100000.0f * (mi * mj - 1.0f);
        for (int h = 0; h < 12; ++h) {
            const float* kh = kT + ((size_t)((b * 12 + h) * 16) << 9) + j;
            float qk = 0.f;
            #pragma unroll
            for (int c = 0; c < 16; ++c) qk += q_s[h * 16 + c] * kh[c << 9];
            const float* kp = kptsT + ((size_t)((b * 12 + h) * 12) << 9) + j;
            float d2 = 0.f;
            #pragma unroll
            for (int px = 0; px < 12; ++px) {
                float d = qp_s[h * 12 + px] - kp[px << 9];
                d2 += d * d;
            }
            l_s[h * 512 + j] = QK_SCALE * qk - 0.5f * hw_s[h] * d2
                               + BB_SCALE * bpb[h] + maskterm;
        }
    }
    __syncthreads();

    // phase 2: logits += BB_SCALE * (p @ wb), prefetched tile pipeline
    {
        const int jj = t & 31, cq = t >> 5;   // jj = row in tile, cq = c-group of 16
        for (int tile = 0; tile < 16; ++tile) {
            // write prefetched tile to LDS
            #pragma unroll
            for (int u = 0; u < 4; ++u) {
                int q = u * 256 + t;
                *(float4*)&p_tile[(q >> 5) * 132 + (q & 31) * 4] = pre[u];
            }
            __syncthreads();
            // issue next tile's loads (consumed at next iteration's LDS write)
            if (tile < 15) {
                const float* nsrc = psrc + (size_t)(tile + 1) * 32 * 128;
                #pragma unroll
                for (int u = 0; u < 4; ++u) {
                    int q = u * 256 + t;
                    pre[u] = *(const float4*)&nsrc[(size_t)(q >> 5) * 128 + (q & 31) * 4];
                }
            }
            // compute partial[12] over this thread's 16 c
            float partial[12];
            #pragma unroll
            for (int h = 0; h < 12; ++h) partial[h] = 0.f;
            #pragma unroll
            for (int c4 = 0; c4 < 4; ++c4) {
                float4 pv = *(const float4*)&p_tile[jj * 132 + cq * 16 + c4 * 4];
                float pvals[4] = {pv.x, pv.y, pv.z, pv.w};
                #pragma unroll
                for (int u = 0; u < 4; ++u) {
                    float pu = pvals[u];
                    int c = cq * 16 + c4 * 4 + u;
                    float4 w0 = *(const float4*)&wb_s[c * 12 + 0];
                    float4 w1 = *(const float4*)&wb_s[c * 12 + 4];
                    float4 w2 = *(const float4*)&wb_s[c * 12 + 8];
                    partial[0] += pu * w0.x; partial[1] += pu * w0.y;
                    partial[2] += pu * w0.z; partial[3] += pu * w0.w;
                    partial[4] += pu * w1.x; partial[5] += pu * w1.y;
                    partial[6] += pu * w1.z; partial[7] += pu * w1.w;
                    partial[8] += pu * w2.x; partial[9] += pu * w2.y;
                    partial[10] += pu * w2.z; partial[11] += pu * w2.w;
                }
            }
            __syncthreads();               // done reading p_tile; red overlays it
            #pragma unroll
            for (int h = 0; h < 12; ++h) red[t * 12 + h] = partial[h];
            __syncthreads();
            int j0 = tile * 32;
            for (int idx = t; idx < 384; idx += 256) {
                int j2 = idx / 12, h2 = idx % 12;
                float sum = 0.f;
                #pragma unroll
                for (int cq2 = 0; cq2 < 8; ++cq2) sum += red[(cq2 * 32 + j2) * 12 + h2];
                l_s[h2 * 512 + j0 + j2] += BB_SCALE * sum;
            }
            __syncthreads();               // gather done before next LDS write
        }
    }

    // phase 3: softmax per head; wave w handles heads 3w..3w+2; also write a_t[j][h]
    {
        const int w = t >> 6, lane = t & 63;
        for (int h = w * 3; h < w * 3 + 3; ++h) {
            float m = -1e30f;
            for (int j = lane; j < 512; j += 64) m = fmaxf(m, l_s[h * 512 + j]);
            #pragma unroll
            for (int o = 32; o > 0; o >>= 1) m = fmaxf(m, __shfl_xor(m, o, 64));
            float ssum = 0.f;
            for (int j = lane; j < 512; j += 64) {
                float e = __expf(l_s[h * 512 + j] - m);
                l_s[h * 512 + j] = e;
                ssum += e;
            }
            #pragma unroll
            for (int o = 32; o > 0; o >>= 1) ssum += __shfl_xor(ssum, o, 64);
            float inv = 1.0f / ssum;
            for (int j = lane; j < 512; j += 64) {
                float v = l_s[h * 512 + j] * inv;
                l_s[h * 512 + j] = v;
                a_t[j * 12 + h] = v;
            }
        }
    }
    __syncthreads();

    // phase 4: o = a@v (192) and o_pt_g = a@v_pts (288), wave-per-output
    {
        const int w = t >> 6, lane = t & 63;
        for (int oi = w; oi < 480; oi += 4) {
            const float* src; int h;
            if (oi < 192) { h = oi >> 4; src = vT + ((size_t)((b * 12 + h) * 16 + (oi & 15)) << 9); }
            else { int o2 = oi - 192; h = o2 / 24; src = vptsT + ((size_t)((b * 12 + h) * 24 + (o2 % 24)) << 9); }
            float acc = 0.f;
            for (int j = lane; j < 512; j += 64) acc += l_s[h * 512 + j] * src[j];
            #pragma unroll
            for (int o = 32; o > 0; o >>= 1) acc += __shfl_xor(acc, o, 64);
            if (lane == 0) {
                if (oi < 192) feats[(size_t)row * 2112 + oi] = acc;
                else          optg_s[oi - 192] = acc;
            }
        }
    }
    __syncthreads();

    // epilogue: o_pt = R^T (o_pt_g - t), norms
    if (t < 96) {
        float gx = optg_s[t * 3 + 0] - T_s[0];
        float gy = optg_s[t * 3 + 1] - T_s[1];
        float gz = optg_s[t * 3 + 2] - T_s[2];
        float ox = R_s[0] * gx + R_s[3] * gy + R_s[6] * gz;
        float oy = R_s[1] * gx + R_s[4] * gy + R_s[7] * gz;
        float oz = R_s[2] * gx + R_s[5] * gy + R_s[8] * gz;
        float nrm = sqrtf(ox * ox + oy * oy + oz * oz + 1e-8f);
        size_t fb = (size_t)row * 2112;
        feats[fb + 192 + t] = ox;
        feats[fb + 288 + t] = oy;
        feats[fb + 384 + t] = oz;
        feats[fb + 480 + t] = nrm;
    }

    // phase 5: o_pair[h][c] = sum_j a[h][j] * p[i][j][c]  -- direct p stream
    {
        const int cg = t & 31, js = t >> 5;
        float acc[12][4];
        #pragma unroll
        for (int h = 0; h < 12; ++h) {
            #pragma unroll
            for (int u = 0; u < 4; ++u) acc[h][u] = 0.f;
        }
        for (int jj5 = 0; jj5 < 64; ++jj5) {
            int j = js * 64 + jj5;
            float4 pv = *(const float4*)&psrc[(size_t)j * 128 + cg * 4];
            float4 a0 = *(const float4*)&a_t[j * 12 + 0];
            float4 a1 = *(const float4*)&a_t[j * 12 + 4];
            float4 a2 = *(const float4*)&a_t[j * 12 + 8];
            acc[0][0] += a0.x * pv.x; acc[0][1] += a0.x * pv.y; acc[0][2] += a0.x * pv.z; acc[0][3] += a0.x * pv.w;
            acc[1][0] += a0.y * pv.x; acc[1][1] += a0.y * pv.y; acc[1][2] += a0.y * pv.z; acc[1][3] += a0.y * pv.w;
            acc[2][0] += a0.z * pv.x; acc[2][1] += a0.z * pv.y; acc[2][2] += a0.z * pv.z; acc[2][3] += a0.z * pv.w;
            acc[3][0] += a0.w * pv.x; acc[3][1] += a0.w * pv.y; acc[3][2] += a0.w * pv.z; acc[3][3] += a0.w * pv.w;
            acc[4][0] += a1.x * pv.x; acc[4][1] += a1.x * pv.y; acc[4][2] += a1.x * pv.z; acc[4][3] += a1.x * pv.w;
            acc[5][0] += a1.y * pv.x; acc[5][1] += a1.y * pv.y; acc[5][2] += a1.y * pv.z; acc[5][3] += a1.y * pv.w;
            acc[6][0] += a1.z * pv.x; acc[6][1] += a1.z * pv.y; acc[6][2] += a1.z * pv.z; acc[6][3] += a1.z * pv.w;
            acc[7][0] += a1.w * pv.x; acc[7][1] += a1.w * pv.y; acc[7][2] += a1.w * pv.z; acc[7][3] += a1.w * pv.w;
            acc[8][0] += a2.x * pv.x; acc[8][1] += a2.x * pv.y; acc[8][2] += a2.x * pv.z; acc[8][3] += a2.x * pv.w;
            acc[9][0] += a2.y * pv.x; acc[9][1] += a2.y * pv.y; acc[9][2] += a2.y * pv.z; acc[9][3] += a2.y * pv.w;
            acc[10][0] += a2.z * pv.x; acc[10][1] += a2.z * pv.y; acc[10][2] += a2.z * pv.z; acc[10][3] += a2.z * pv.w;
            acc[11][0] += a2.w * pv.x; acc[11][1] += a2.w * pv.y; acc[11][2] += a2.w * pv.z; acc[11][3] += a2.w * pv.w;
        }
        __syncthreads();                       // a_t dead; red2 overlays everything
        #pragma unroll
        for (int h = 0; h < 12; ++h) {
            #pragma unroll
            for (int u = 0; u < 4; ++u) red2[(h * 4 + u) * 256 + t] = acc[h][u];
        }
        __syncthreads();
        size_t fb = (size_t)row * 2112 + 576;
        for (int o = t; o < 1536; o += 256) {
            int h = o >> 7, c = o & 127, cg2 = c >> 2, u = c & 3;
            float sum = 0.f;
            #pragma unroll
            for (int js2 = 0; js2 < 8; ++js2) sum += red2[(h * 4 + u) * 256 + js2 * 32 + cg2];
            feats[fb + o] = sum;
        }
    }
}

// ---------------------------------------------------------------------------
// K4: tiled GEMM: out(1024x384) = f(A(1024xK) @ W(Kx384) + bias [+resid]).
// Block = 8 rows x 128 cols, 256 threads, grid = 128*3 = 384.
// A chunk transposed in LDS (broadcast b128 reads); W streamed from L2.
// ---------------------------------------------------------------------------
__global__ __launch_bounds__(256) void k_gemm(
    const float* __restrict__ A, const float* __restrict__ W,
    const float* __restrict__ bias, const float* __restrict__ resid,
    float* __restrict__ out, int K, int do_relu)
{
    __shared__ __align__(16) float a_t[64 * 12];
    const int rowblk = blockIdx.x / 3, cg = blockIdx.x % 3;
    const int row0 = rowblk * 8;
    const int t = threadIdx.x;
    const int c = t & 127, rh = t >> 7;
    const int C = cg * 128 + c;
    float acc[4] = {0.f, 0.f, 0.f, 0.f};
    for (int k0 = 0; k0 < K; k0 += 64) {
        __syncthreads();
        for (int idx = t; idx < 512; idx += 256) {
            int r = idx >> 6, kk = idx & 63;
            a_t[kk * 12 + r] = A[(size_t)(row0 + r) * K + k0 + kk];
        }
        __syncthreads();
        const float* wp = W + (size_t)k0 * 384 + C;
        #pragma unroll 8
        for (int kk = 0; kk < 64; ++kk) {
            float wv = wp[(size_t)kk * 384];
            float4 av = *(const float4*)&a_t[kk * 12 + rh * 4];
            acc[0] += av.x * wv; acc[1] += av.y * wv;
            acc[2] += av.z * wv; acc[3] += av.w * wv;
        }
    }
    float bv = bias[C];
    #pragma unroll
    for (int r = 0; r < 4; ++r) {
        int rowi = row0 + rh * 4 + r;
        float v = acc[r] + bv;
        if (do_relu) v = fmaxf(v, 0.f);
        if (resid) v += resid[(size_t)rowi * 384 + C];
        out[(size_t)rowi * 384 + C] = v;
    }
}

// ---------------------------------------------------------------------------
// K5: LayerNorm over rows of (1024, 384). One wave per row. grid 256 x 256.
// ---------------------------------------------------------------------------
__global__ __launch_bounds__(256) void k_ln(
    const float* __restrict__ x, const float* __restrict__ g,
    const float* __restrict__ bta, float* __restrict__ o)
{
    const int wid = (blockIdx.x * 256 + threadIdx.x) >> 6;
    const int lane = threadIdx.x & 63;
    const float* xr = x + (size_t)wid * 384;
    float v[6], sum = 0.f, sq = 0.f;
    #pragma unroll
    for (int u = 0; u < 6; ++u) {
        v[u] = xr[lane + 64 * u];
        sum += v[u]; sq += v[u] * v[u];
    }
    #pragma unroll
    for (int off = 32; off > 0; off >>= 1) {
        sum += __shfl_xor(sum, off, 64);
        sq  += __shfl_xor(sq, off, 64);
    }
    float mean = sum * (1.f / 384.f);
    float var = sq * (1.f / 384.f) - mean * mean;
    float rst = rsqrtf(var + 1e-5f);
    #pragma unroll
    for (int u = 0; u < 6; ++u) {
        int cc = lane + 64 * u;
        o[(size_t)wid * 384 + cc] = (v[u] - mean) * rst * g[cc] + bta[cc];
    }
}

// ---------------------------------------------------------------------------
// K6: backbone update. One wave per row.
// ---------------------------------------------------------------------------
__global__ __launch_bounds__(256) void k_bb(
    const float* __restrict__ sfin, const float* __restrict__ w_bb,
    const float* __restrict__ b_bb,
    const float* __restrict__ t_rot, const float* __restrict__ t_trans,
    float* __restrict__ rot_out, float* __restrict__ trans_out)
{
    const int wid = (blockIdx.x * 256 + threadIdx.x) >> 6;
    const int lane = threadIdx.x & 63;
    const float* srow = sfin + (size_t)wid * 384;
    float u[6] = {0.f, 0.f, 0.f, 0.f, 0.f, 0.f};
    for (int k = lane; k < 384; k += 64) {
        float sv = srow[k];
        #pragma unroll
        for (int j = 0; j < 6; ++j) u[j] += sv * w_bb[k * 6 + j];
    }
    #pragma unroll
    for (int j = 0; j < 6; ++j) {
        #pragma unroll
        for (int o = 32; o > 0; o >>= 1) u[j] += __shfl_xor(u[j], o, 64);
    }
    if (lane == 0) {
        #pragma unroll
        for (int j = 0; j < 6; ++j) u[j] += b_bb[j];
        float bq = u[0], cq = u[1], dq = u[2];
        float inv = rsqrtf(1.f + bq * bq + cq * cq + dq * dq);
        float a = inv, bqn = bq * inv, cqn = cq * inv, dqn = dq * inv;
        float R[9];
        R[0] = a * a + bqn * bqn - cqn * cqn - dqn * dqn;
        R[1] = 2.f * (bqn * cqn - a * dqn);
        R[2] = 2.f * (bqn * dqn + a * cqn);
        R[3] = 2.f * (bqn * cqn + a * dqn);
        R[4] = a * a - bqn * bqn + cqn * cqn - dqn * dqn;
        R[5] = 2.f * (cqn * dqn - a * bqn);
        R[6] = 2.f * (bqn * dqn - a * cqn);
        R[7] = 2.f * (cqn * dqn + a * bqn);
        R[8] = a * a - bqn * bqn - cqn * cqn + dqn * dqn;
        const float* Rt = t_rot + (size_t)wid * 9;
        #pragma unroll
        for (int i2 = 0; i2 < 3; ++i2) {
            #pragma unroll
            for (int k2 = 0; k2 < 3; ++k2) {
                rot_out[(size_t)wid * 9 + i2 * 3 + k2] =
                    Rt[i2 * 3 + 0] * R[0 + k2] + Rt[i2 * 3 + 1] * R[3 + k2] + Rt[i2 * 3 + 2] * R[6 + k2];
            }
            trans_out[(size_t)wid * 3 + i2] =
                Rt[i2 * 3 + 0] * u[3] + Rt[i2 * 3 + 1] * u[4] + Rt[i2 * 3 + 2] * u[5]
                + t_trans[(size_t)wid * 3 + i2];
        }
    }
}

// ---------------------------------------------------------------------------
extern "C" void kernel_launch(void* const* d_in, const int* in_sizes, int n_in,
                              void* d_out, int out_size, void* d_ws, size_t ws_size,
                              hipStream_t stream) {
    const float* s      = (const float*)d_in[0];
    const float* p      = (const float*)d_in[1];
    const float* t_rot  = (const float*)d_in[2];
    const float* t_trans= (const float*)d_in[3];
    const float* mask   = (const float*)d_in[4];
    const float* wq     = (const float*)d_in[5];
    const float* bq     = (const float*)d_in[6];
    const float* wkv    = (const float*)d_in[7];
    const float* bkv    = (const float*)d_in[8];
    const float* wqp    = (const float*)d_in[9];
    const float* bqp    = (const float*)d_in[10];
    const float* wkvp   = (const float*)d_in[11];
    const float* bkvp   = (const float*)d_in[12];
    const float* wb     = (const float*)d_in[13];
    const float* bpb    = (const float*)d_in[14];
    const float* hwts   = (const float*)d_in[15];
    const float* w_out  = (const float*)d_in[16];
    const float* b_out  = (const float*)d_in[17];
    const float* ln1s   = (const float*)d_in[18];
    const float* ln1b   = (const float*)d_in[19];
    const float* wt1    = (const float*)d_in[20];
    const float* bt1    = (const float*)d_in[21];
    const float* wt2    = (const float*)d_in[22];
    const float* bt2    = (const float*)d_in[23];
    const float* wt3    = (const float*)d_in[24];
    const float* bt3    = (const float*)d_in[25];
    const float* ln2s   = (const float*)d_in[26];
    const float* ln2b   = (const float*)d_in[27];
    const float* w_bb   = (const float*)d_in[28];
    const float* b_bb   = (const float*)d_in[29];
    float* out = (float*)d_out;
    float* ws  = (float*)d_ws;

    float* q_o   = ws;                  // 196608
    float* kT    = q_o + 196608;        // 196608
    float* vT    = kT + 196608;         // 196608
    float* qpl   = vT + 196608;         // 147456
    float* qpg   = qpl + 147456;        // 147456
    float* kvpl  = qpg + 147456;        // 442368  (dead after k_pts -> s1raw)
    float* kptsT = kvpl + 442368;       // 147456
    float* vptsT = kptsT + 147456;      // 294912
    float* feats = vptsT + 294912;      // 2162688 (dead after g1 -> s2raw)
    float* s1    = feats + 2162688;     // 393216
    float* h1    = s1 + 393216;         // 393216
    float* h2    = h1 + 393216;         // 393216
    float* s1raw = kvpl;
    float* s2raw = feats;

    k_proj<<<1024, 256, 0, stream>>>(s, wq, bq, wkv, bkv, wqp, bqp, wkvp, bkvp,
                                     q_o, kT, vT, qpl, kvpl);
    k_pts<<<1024, 192, 0, stream>>>(qpl, kvpl, t_rot, t_trans, qpg, kptsT, vptsT);
    k_attn<<<1024, 256, 0, stream>>>(q_o, kT, vT, qpg, kptsT, vptsT, p, wb, bpb,
                                     hwts, mask, t_rot, t_trans, feats);
    k_gemm<<<384, 256, 0, stream>>>(feats, w_out, b_out, s, s1raw, 2112, 0);
    k_ln<<<256, 256, 0, stream>>>(s1raw, ln1s, ln1b, s1);
    k_gemm<<<384, 256, 0, stream>>>(s1, wt1, bt1, nullptr, h1, 384, 1);
    k_gemm<<<384, 256, 0, stream>>>(h1, wt2, bt2, nullptr, h2, 384, 1);
    k_gemm<<<384, 256, 0, stream>>>(h2, wt3, bt3, s1, s2raw, 384, 0);
    k_ln<<<256, 256, 0, stream>>>(s2raw, ln2s, ln2b, out);
    k_bb<<<256, 256, 0, stream>>>(out, w_bb, b_bb, t_rot, t_trans,
                                  out + 393216, out + 402432);
}

// Round 3
// 511.317 us; speedup vs baseline: 2.1256x; 1.2847x over previous
//
#include <hip/hip_runtime.h>
#include <math.h>

#define QK_SCALE 0.14433756729740643f   // 1/sqrt(3*16)
#define BB_SCALE 0.57735026918962576f   // 1/sqrt(3)
#define HW_COEF  0.13608276348795434f   // 1/sqrt(54)

// ---------------------------------------------------------------------------
// K_PROJ: tiled GEMM (1024x384)@(384x1152 composite) with scatter epilogue.
// 32 rows x 128 cols per block, 4x4 per thread. grid = (32, 9).
// ---------------------------------------------------------------------------
__global__ __launch_bounds__(256) void k_proj(
    const float* __restrict__ s,
    const float* __restrict__ wq,  const float* __restrict__ bq,
    const float* __restrict__ wkv, const float* __restrict__ bkv,
    const float* __restrict__ wqp, const float* __restrict__ bqp,
    const float* __restrict__ wkvp,const float* __restrict__ bkvp,
    float* __restrict__ q_o,    // (B,N,192)
    float* __restrict__ kT2,    // (B,12,512,16)
    float* __restrict__ vT,     // (B,12,16,512)
    float* __restrict__ qpl,    // (B,N,48,3) local
    float* __restrict__ kvpl)   // (B,N,144,3) local
{
    __shared__ __align__(16) float A_t[64 * 36];
    __shared__ __align__(16) float W_s[64 * 132];
    const int row0 = blockIdx.x * 32;
    const int C0 = blockIdx.y * 128;
    const int t = threadIdx.x;
    const int cq = t & 31, rq = t >> 5;
    float acc[4][4] = {};
    for (int ch = 0; ch < 6; ++ch) {
        const int k0 = ch * 64;
        __syncthreads();
        for (int idx = t; idx < 512; idx += 256) {
            int r = idx & 31, kq = idx >> 5;
            float4 a = *(const float4*)&s[(size_t)(row0 + r) * 384 + k0 + kq * 4];
            A_t[(kq * 4 + 0) * 36 + r] = a.x;
            A_t[(kq * 4 + 1) * 36 + r] = a.y;
            A_t[(kq * 4 + 2) * 36 + r] = a.z;
            A_t[(kq * 4 + 3) * 36 + r] = a.w;
        }
        for (int idx = t; idx < 2048; idx += 256) {
            int kk = idx >> 5, c4 = idx & 31;
            int C4 = C0 + c4 * 4;
            const float* w; int sub, wcols;
            if (C4 < 192)      { w = wq;   sub = C4;       wcols = 192; }
            else if (C4 < 576) { w = wkv;  sub = C4 - 192; wcols = 384; }
            else if (C4 < 720) { w = wqp;  sub = C4 - 576; wcols = 144; }
            else               { w = wkvp; sub = C4 - 720; wcols = 432; }
            *(float4*)&W_s[kk * 132 + c4 * 4] =
                *(const float4*)&w[(size_t)(k0 + kk) * wcols + sub];
        }
        __syncthreads();
        #pragma unroll 8
        for (int kk = 0; kk < 64; ++kk) {
            float4 a4 = *(const float4*)&A_t[kk * 36 + rq * 4];
            float4 w4 = *(const float4*)&W_s[kk * 132 + cq * 4];
            acc[0][0] += a4.x * w4.x; acc[0][1] += a4.x * w4.y; acc[0][2] += a4.x * w4.z; acc[0][3] += a4.x * w4.w;
            acc[1][0] += a4.y * w4.x; acc[1][1] += a4.y * w4.y; acc[1][2] += a4.y * w4.z; acc[1][3] += a4.y * w4.w;
            acc[2][0] += a4.z * w4.x; acc[2][1] += a4.z * w4.y; acc[2][2] += a4.z * w4.z; acc[2][3] += a4.z * w4.w;
            acc[3][0] += a4.w * w4.x; acc[3][1] += a4.w * w4.y; acc[3][2] += a4.w * w4.z; acc[3][3] += a4.w * w4.w;
        }
    }
    // scatter epilogue with bias
    #pragma unroll
    for (int r = 0; r < 4; ++r) {
        int row = row0 + rq * 4 + r;
        int b = row >> 9, n = row & 511;
        #pragma unroll
        for (int u = 0; u < 4; ++u) {
            int col = C0 + cq * 4 + u;
            float v = acc[r][u];
            if (col < 192) {
                q_o[(size_t)row * 192 + col] = v + bq[col];
            } else if (col < 576) {
                int sub = col - 192;
                v += bkv[sub];
                int h = sub >> 5, rr = sub & 31;
                if (rr < 16) kT2[((size_t)((b * 12 + h) << 9) + n) * 16 + rr] = v;
                else         vT[(((b * 12 + h) * 16 + (rr - 16)) << 9) + n] = v;
            } else if (col < 720) {
                int sub = col - 576;
                v += bqp[sub];
                int axis = sub / 48, rem = sub % 48;
                qpl[(size_t)row * 144 + rem * 3 + axis] = v;
            } else {
                int sub = col - 720;
                v += bkvp[sub];
                int axis = sub / 144, rem = sub % 144;
                kvpl[(size_t)row * 432 + rem * 3 + axis] = v;
            }
        }
    }
}

// ---------------------------------------------------------------------------
// K2: local->global point transform + scatter (kpT2 j-major, vptsT col-major)
// ---------------------------------------------------------------------------
__global__ __launch_bounds__(192) void k_pts(
    const float* __restrict__ qpl, const float* __restrict__ kvpl,
    const float* __restrict__ t_rot, const float* __restrict__ t_trans,
    float* __restrict__ qpg,    // (B,N,144)
    float* __restrict__ kpT2,   // (B,12,512,12)
    float* __restrict__ vptsT)  // (B,12,24,512)
{
    const int row = blockIdx.x;
    const int b = row >> 9, n = row & 511;
    const int t = threadIdx.x;
    __shared__ float R[9], T[3];
    if (t < 9) R[t] = t_rot[(size_t)row * 9 + t];
    if (t < 3) T[t] = t_trans[(size_t)row * 3 + t];
    __syncthreads();
    float lx, ly, lz;
    if (t < 48) {
        lx = qpl[(size_t)row * 144 + t * 3 + 0];
        ly = qpl[(size_t)row * 144 + t * 3 + 1];
        lz = qpl[(size_t)row * 144 + t * 3 + 2];
    } else {
        int pp = t - 48;
        lx = kvpl[(size_t)row * 432 + pp * 3 + 0];
        ly = kvpl[(size_t)row * 432 + pp * 3 + 1];
        lz = kvpl[(size_t)row * 432 + pp * 3 + 2];
    }
    float gx = R[0] * lx + R[1] * ly + R[2] * lz + T[0];
    float gy = R[3] * lx + R[4] * ly + R[5] * lz + T[1];
    float gz = R[6] * lx + R[7] * ly + R[8] * lz + T[2];
    if (t < 48) {
        qpg[(size_t)row * 144 + t * 3 + 0] = gx;
        qpg[(size_t)row * 144 + t * 3 + 1] = gy;
        qpg[(size_t)row * 144 + t * 3 + 2] = gz;
    } else {
        int pp = t - 48;
        int h = pp / 12, pt = pp % 12;
        if (pt < 4) {
            int base = ((size_t)0 + ((b * 12 + h) << 9) + n) * 12 + pt * 3;
            kpT2[base + 0] = gx; kpT2[base + 1] = gy; kpT2[base + 2] = gz;
        } else {
            int base = (((b * 12 + h) * 24 + (pt - 4) * 3) << 9) + n;
            vptsT[base] = gx; vptsT[base + 512] = gy; vptsT[base + 1024] = gz;
        }
    }
}

// ---------------------------------------------------------------------------
// K3: attention mega-kernel. One block per (b,i), 256 threads.
// smem[0..6144)  = l_s [12][512]
// smem[6144..)   = red [8][32][12] (phase 2) -> a_t [512][12] (phases 3+)
// red2 overlay   = smem[0..12288) (phase 5 reduction)
// ---------------------------------------------------------------------------
__global__ __launch_bounds__(256) void k_attn(
    const float* __restrict__ q_o,   // (B,N,192)
    const float* __restrict__ kT2,   // (B,12,512,16)
    const float* __restrict__ vT,    // (B,12,16,512)
    const float* __restrict__ qpg,   // (B,N,144)
    const float* __restrict__ kpT2,  // (B,12,512,12)
    const float* __restrict__ vptsT, // (B,12,24,512)
    const float* __restrict__ p,     // (B,N,N,128)
    const float* __restrict__ wb,    // (128,12)
    const float* __restrict__ bpb,   // (12)
    const float* __restrict__ hwts,  // (12)
    const float* __restrict__ mask,  // (B,N)
    const float* __restrict__ t_rot, const float* __restrict__ t_trans,
    float* __restrict__ feats)       // (B,N,2112)
{
    __shared__ __align__(16) float smem[12288];
    __shared__ __align__(16) float q_s[192];
    __shared__ __align__(16) float qp_s[144];
    __shared__ __align__(16) float optg_s[288];
    __shared__ float R_s[9], T_s[3], hw_s[12], misc_s[4];

    float* l_s  = smem;
    float* red  = smem + 6144;   // [8][32][12] during phase 2
    float* a_t  = smem + 6144;   // [512][12] from phase 3
    float* red2 = smem;          // [48][256] phase 5

    const int row = blockIdx.x;
    const int b = row >> 9, i = row & 511;
    const int t = threadIdx.x;
    const int cg = t & 31, js = t >> 5;
    const float* psrc = p + ((size_t)(b * 512 + i) * 512) * 128;

    // phase 0: stage per-row data
    for (int idx = t; idx < 192; idx += 256)  q_s[idx] = q_o[(size_t)row * 192 + idx];
    for (int idx = t; idx < 144; idx += 256)  qp_s[idx] = qpg[(size_t)row * 144 + idx];
    if (t < 12) {
        float x = hwts[t];
        float sp = (x > 20.f) ? x : log1pf(__expf(x));
        hw_s[t] = sp * HW_COEF;
    }
    if (t < 9) R_s[t] = t_rot[(size_t)row * 9 + t];
    if (t < 3) T_s[t] = t_trans[(size_t)row * 3 + t];
    if (t == 0) misc_s[0] = mask[row];

    // wb -> registers (4 c x 12 h per thread)
    float wbr[4][12];
    #pragma unroll
    for (int u = 0; u < 4; ++u)
        #pragma unroll
        for (int h = 0; h < 12; ++h)
            wbr[u][h] = wb[(cg * 4 + u) * 12 + h];

    // prefetch p tile 0 (latency hides under phase 1)
    float4 pv[4];
    #pragma unroll
    for (int jl = 0; jl < 4; ++jl)
        pv[jl] = *(const float4*)&psrc[(size_t)(js * 4 + jl) * 128 + cg * 4];

    __syncthreads();
    const float mi = misc_s[0];

    // phase 1: base logits = qk*scale + pt_att + bpb + mask
    {
        const float4* q4 = (const float4*)q_s;
        const float4* qp4 = (const float4*)qp_s;
        for (int jr = 0; jr < 2; ++jr) {
            int j = t + jr * 256;
            float mj = mask[b * 512 + j];
            float maskterm = 100000.0f * (mi * mj - 1.0f);
            for (int h = 0; h < 12; ++h) {
                const float4* k4 = (const float4*)&kT2[((size_t)((b * 12 + h) << 9) + j) * 16];
                float qk = 0.f;
                #pragma unroll
                for (int c4 = 0; c4 < 4; ++c4) {
                    float4 qv = q4[h * 4 + c4], kv = k4[c4];
                    qk += qv.x * kv.x + qv.y * kv.y + qv.z * kv.z + qv.w * kv.w;
                }
                const float4* kp4 = (const float4*)&kpT2[((size_t)((b * 12 + h) << 9) + j) * 12];
                float d2 = 0.f;
                #pragma unroll
                for (int x = 0; x < 3; ++x) {
                    float4 qp = qp4[h * 3 + x], kp = kp4[x];
                    float dx = qp.x - kp.x, dy = qp.y - kp.y;
                    float dz = qp.z - kp.z, dw = qp.w - kp.w;
                    d2 += dx * dx + dy * dy + dz * dz + dw * dw;
                }
                l_s[h * 512 + j] = QK_SCALE * qk - 0.5f * hw_s[h] * d2
                                   + BB_SCALE * bpb[h] + maskterm;
            }
        }
    }
    __syncthreads();

    // phase 2: l_s += BB_SCALE * (p @ wb); p streamed once, wb in registers
    for (int tile = 0; tile < 16; ++tile) {
        int j0 = tile * 32;
        float4 nxt[4];
        if (tile < 15) {
            #pragma unroll
            for (int jl = 0; jl < 4; ++jl)
                nxt[jl] = *(const float4*)&psrc[(size_t)(j0 + 32 + js * 4 + jl) * 128 + cg * 4];
        }
        #pragma unroll
        for (int jl = 0; jl < 4; ++jl) {
            float partial[12];
            #pragma unroll
            for (int h = 0; h < 12; ++h)
                partial[h] = pv[jl].x * wbr[0][h] + pv[jl].y * wbr[1][h]
                           + pv[jl].z * wbr[2][h] + pv[jl].w * wbr[3][h];
            #pragma unroll
            for (int h = 0; h < 12; ++h) {
                partial[h] += __shfl_xor(partial[h], 1, 64);
                partial[h] += __shfl_xor(partial[h], 2, 64);
            }
            if ((cg & 3) == 0) {
                int jj = js * 4 + jl;
                #pragma unroll
                for (int h = 0; h < 12; ++h)
                    red[((cg >> 2) * 32 + jj) * 12 + h] = partial[h];
            }
        }
        __syncthreads();
        for (int idx = t; idx < 384; idx += 256) {
            int h2 = idx >> 5, j2 = idx & 31;
            float sum = 0.f;
            #pragma unroll
            for (int q = 0; q < 8; ++q) sum += red[(q * 32 + j2) * 12 + h2];
            l_s[h2 * 512 + j0 + j2] += BB_SCALE * sum;
        }
        __syncthreads();
        #pragma unroll
        for (int jl = 0; jl < 4; ++jl) pv[jl] = nxt[jl];
    }

    // phase 3: softmax per head; wave w handles heads 3w..3w+2; write a_t[j][h]
    {
        const int w = t >> 6, lane = t & 63;
        for (int h = w * 3; h < w * 3 + 3; ++h) {
            float m = -1e30f;
            for (int j = lane; j < 512; j += 64) m = fmaxf(m, l_s[h * 512 + j]);
            #pragma unroll
            for (int o = 32; o > 0; o >>= 1) m = fmaxf(m, __shfl_xor(m, o, 64));
            float ssum = 0.f;
            for (int j = lane; j < 512; j += 64) {
                float e = __expf(l_s[h * 512 + j] - m);
                l_s[h * 512 + j] = e;
                ssum += e;
            }
            #pragma unroll
            for (int o = 32; o > 0; o >>= 1) ssum += __shfl_xor(ssum, o, 64);
            float inv = 1.0f / ssum;
            for (int j = lane; j < 512; j += 64) {
                float v = l_s[h * 512 + j] * inv;
                l_s[h * 512 + j] = v;
                a_t[j * 12 + h] = v;
            }
        }
    }
    __syncthreads();

    // phase 4: o = a@v (192) and o_pt_g = a@v_pts (288), wave-per-output, f4
    {
        const int w = t >> 6, lane = t & 63;
        const float4* l4 = (const float4*)l_s;
        for (int oi = w; oi < 480; oi += 4) {
            const float* src; int h;
            if (oi < 192) { h = oi >> 4; src = vT + ((size_t)((b * 12 + h) * 16 + (oi & 15)) << 9); }
            else { int o2 = oi - 192; h = o2 / 24; src = vptsT + ((size_t)((b * 12 + h) * 24 + (o2 % 24)) << 9); }
            const float4* s4 = (const float4*)src;
            float acc = 0.f;
            #pragma unroll
            for (int r2 = 0; r2 < 2; ++r2) {
                int jq = lane + r2 * 64;
                float4 a4 = l4[h * 128 + jq];
                float4 v4 = s4[jq];
                acc += a4.x * v4.x + a4.y * v4.y + a4.z * v4.z + a4.w * v4.w;
            }
            #pragma unroll
            for (int o = 32; o > 0; o >>= 1) acc += __shfl_xor(acc, o, 64);
            if (lane == 0) {
                if (oi < 192) feats[(size_t)row * 2112 + oi] = acc;
                else          optg_s[oi - 192] = acc;
            }
        }
    }
    __syncthreads();

    // epilogue: o_pt = R^T (o_pt_g - t), norms
    if (t < 96) {
        float gx = optg_s[t * 3 + 0] - T_s[0];
        float gy = optg_s[t * 3 + 1] - T_s[1];
        float gz = optg_s[t * 3 + 2] - T_s[2];
        float ox = R_s[0] * gx + R_s[3] * gy + R_s[6] * gz;
        float oy = R_s[1] * gx + R_s[4] * gy + R_s[7] * gz;
        float oz = R_s[2] * gx + R_s[5] * gy + R_s[8] * gz;
        float nrm = sqrtf(ox * ox + oy * oy + oz * oz + 1e-8f);
        size_t fb = (size_t)row * 2112;
        feats[fb + 192 + t] = ox;
        feats[fb + 288 + t] = oy;
        feats[fb + 384 + t] = oz;
        feats[fb + 480 + t] = nrm;
    }

    // phase 5: o_pair[h][c] = sum_j a[h][j] * p[i][j][c] -- second p stream
    {
        float acc[12][4];
        #pragma unroll
        for (int h = 0; h < 12; ++h) {
            #pragma unroll
            for (int u = 0; u < 4; ++u) acc[h][u] = 0.f;
        }
        for (int jj5 = 0; jj5 < 64; ++jj5) {
            int j = js * 64 + jj5;
            float4 pvv = *(const float4*)&psrc[(size_t)j * 128 + cg * 4];
            float4 a0 = *(const float4*)&a_t[j * 12 + 0];
            float4 a1 = *(const float4*)&a_t[j * 12 + 4];
            float4 a2 = *(const float4*)&a_t[j * 12 + 8];
            acc[0][0] += a0.x * pvv.x; acc[0][1] += a0.x * pvv.y; acc[0][2] += a0.x * pvv.z; acc[0][3] += a0.x * pvv.w;
            acc[1][0] += a0.y * pvv.x; acc[1][1] += a0.y * pvv.y; acc[1][2] += a0.y * pvv.z; acc[1][3] += a0.y * pvv.w;
            acc[2][0] += a0.z * pvv.x; acc[2][1] += a0.z * pvv.y; acc[2][2] += a0.z * pvv.z; acc[2][3] += a0.z * pvv.w;
            acc[3][0] += a0.w * pvv.x; acc[3][1] += a0.w * pvv.y; acc[3][2] += a0.w * pvv.z; acc[3][3] += a0.w * pvv.w;
            acc[4][0] += a1.x * pvv.x; acc[4][1] += a1.x * pvv.y; acc[4][2] += a1.x * pvv.z; acc[4][3] += a1.x * pvv.w;
            acc[5][0] += a1.y * pvv.x; acc[5][1] += a1.y * pvv.y; acc[5][2] += a1.y * pvv.z; acc[5][3] += a1.y * pvv.w;
            acc[6][0] += a1.z * pvv.x; acc[6][1] += a1.z * pvv.y; acc[6][2] += a1.z * pvv.z; acc[6][3] += a1.z * pvv.w;
            acc[7][0] += a1.w * pvv.x; acc[7][1] += a1.w * pvv.y; acc[7][2] += a1.w * pvv.z; acc[7][3] += a1.w * pvv.w;
            acc[8][0] += a2.x * pvv.x; acc[8][1] += a2.x * pvv.y; acc[8][2] += a2.x * pvv.z; acc[8][3] += a2.x * pvv.w;
            acc[9][0] += a2.y * pvv.x; acc[9][1] += a2.y * pvv.y; acc[9][2] += a2.y * pvv.z; acc[9][3] += a2.y * pvv.w;
            acc[10][0] += a2.z * pvv.x; acc[10][1] += a2.z * pvv.y; acc[10][2] += a2.z * pvv.z; acc[10][3] += a2.z * pvv.w;
            acc[11][0] += a2.w * pvv.x; acc[11][1] += a2.w * pvv.y; acc[11][2] += a2.w * pvv.z; acc[11][3] += a2.w * pvv.w;
        }
        __syncthreads();    // a_t/l_s dead; red2 overlays
        #pragma unroll
        for (int h = 0; h < 12; ++h) {
            #pragma unroll
            for (int u = 0; u < 4; ++u) red2[(h * 4 + u) * 256 + t] = acc[h][u];
        }
        __syncthreads();
        size_t fb = (size_t)row * 2112 + 576;
        for (int o = t; o < 1536; o += 256) {
            int h = o >> 7, c = o & 127, cg2 = c >> 2, u = c & 3;
            float sum = 0.f;
            #pragma unroll
            for (int js2 = 0; js2 < 8; ++js2) sum += red2[(h * 4 + u) * 256 + js2 * 32 + cg2];
            feats[fb + o] = sum;
        }
    }
}

// ---------------------------------------------------------------------------
// K_GEMM: tiled f32 GEMM, 32r x 128c per block, 4x4/thread, split-K via z.
// A-source = A0 [+A1] [+abias[k]] [relu] (consumer-fused epilogue of prior
// split-K). Output partial at out + z*393216 (no bias/relu on output).
// ---------------------------------------------------------------------------
__global__ __launch_bounds__(256) void k_gemm(
    const float* __restrict__ A0, const float* __restrict__ A1,
    const float* __restrict__ abias, int lda,
    const float* __restrict__ W,
    float* __restrict__ out, int k_chunks, int do_relu)
{
    __shared__ __align__(16) float A_t[64 * 36];
    __shared__ __align__(16) float W_s[64 * 132];
    const int row0 = blockIdx.x * 32;
    const int C0 = blockIdx.y * 128;
    const int k_base = blockIdx.z * k_chunks * 64;
    const int t = threadIdx.x;
    const int cq = t & 31, rq = t >> 5;
    float acc[4][4] = {};
    for (int ch = 0; ch < k_chunks; ++ch) {
        const int k0 = k_base + ch * 64;
        __syncthreads();
        for (int idx = t; idx < 512; idx += 256) {
            int r = idx & 31, kq = idx >> 5;
            float4 a = *(const float4*)&A0[(size_t)(row0 + r) * lda + k0 + kq * 4];
            if (A1) {
                float4 a1 = *(const float4*)&A1[(size_t)(row0 + r) * lda + k0 + kq * 4];
                a.x += a1.x; a.y += a1.y; a.z += a1.z; a.w += a1.w;
            }
            if (abias) {
                float4 ab = *(const float4*)&abias[k0 + kq * 4];
                a.x += ab.x; a.y += ab.y; a.z += ab.z; a.w += ab.w;
            }
            if (do_relu) {
                a.x = fmaxf(a.x, 0.f); a.y = fmaxf(a.y, 0.f);
                a.z = fmaxf(a.z, 0.f); a.w = fmaxf(a.w, 0.f);
            }
            A_t[(kq * 4 + 0) * 36 + r] = a.x;
            A_t[(kq * 4 + 1) * 36 + r] = a.y;
            A_t[(kq * 4 + 2) * 36 + r] = a.z;
            A_t[(kq * 4 + 3) * 36 + r] = a.w;
        }
        for (int idx = t; idx < 2048; idx += 256) {
            int kk = idx >> 5, c4 = idx & 31;
            *(float4*)&W_s[kk * 132 + c4 * 4] =
                *(const float4*)&W[(size_t)(k0 + kk) * 384 + C0 + c4 * 4];
        }
        __syncthreads();
        #pragma unroll 8
        for (int kk = 0; kk < 64; ++kk) {
            float4 a4 = *(const float4*)&A_t[kk * 36 + rq * 4];
            float4 w4 = *(const float4*)&W_s[kk * 132 + cq * 4];
            acc[0][0] += a4.x * w4.x; acc[0][1] += a4.x * w4.y; acc[0][2] += a4.x * w4.z; acc[0][3] += a4.x * w4.w;
            acc[1][0] += a4.y * w4.x; acc[1][1] += a4.y * w4.y; acc[1][2] += a4.y * w4.z; acc[1][3] += a4.y * w4.w;
            acc[2][0] += a4.z * w4.x; acc[2][1] += a4.z * w4.y; acc[2][2] += a4.z * w4.z; acc[2][3] += a4.z * w4.w;
            acc[3][0] += a4.w * w4.x; acc[3][1] += a4.w * w4.y; acc[3][2] += a4.w * w4.z; acc[3][3] += a4.w * w4.w;
        }
    }
    float* outp = out + (size_t)blockIdx.z * 393216;
    #pragma unroll
    for (int r = 0; r < 4; ++r) {
        float4 st = { acc[r][0], acc[r][1], acc[r][2], acc[r][3] };
        *(float4*)&outp[(size_t)(row0 + rq * 4 + r) * 384 + C0 + cq * 4] = st;
    }
}

// ---------------------------------------------------------------------------
// K_LNSUM: out = LN( sum(parts) + bias + resid ). One wave per row.
// ---------------------------------------------------------------------------
__global__ __launch_bounds__(256) void k_lnsum(
    const float* __restrict__ parts, int np,
    const float* __restrict__ bias, const float* __restrict__ resid,
    const float* __restrict__ g, const float* __restrict__ bta,
    float* __restrict__ o)
{
    const int wid = (blockIdx.x * 256 + threadIdx.x) >> 6;
    const int lane = threadIdx.x & 63;
    float v[6], sum = 0.f, sq = 0.f;
    #pragma unroll
    for (int u = 0; u < 6; ++u) {
        int c = lane + 64 * u;
        float x = bias[c] + resid[(size_t)wid * 384 + c];
        for (int q = 0; q < np; ++q)
            x += parts[(size_t)q * 393216 + (size_t)wid * 384 + c];
        v[u] = x; sum += x; sq += x * x;
    }
    #pragma unroll
    for (int off = 32; off > 0; off >>= 1) {
        sum += __shfl_xor(sum, off, 64);
        sq  += __shfl_xor(sq, off, 64);
    }
    float mean = sum * (1.f / 384.f);
    float var = sq * (1.f / 384.f) - mean * mean;
    float rst = rsqrtf(var + 1e-5f);
    #pragma unroll
    for (int u = 0; u < 6; ++u) {
        int c = lane + 64 * u;
        o[(size_t)wid * 384 + c] = (v[u] - mean) * rst * g[c] + bta[c];
    }
}

// ---------------------------------------------------------------------------
// K_BB: backbone update. One wave per row.
// ---------------------------------------------------------------------------
__global__ __launch_bounds__(256) void k_bb(
    const float* __restrict__ sfin, const float* __restrict__ w_bb,
    const float* __restrict__ b_bb,
    const float* __restrict__ t_rot, const float* __restrict__ t_trans,
    float* __restrict__ rot_out, float* __restrict__ trans_out)
{
    const int wid = (blockIdx.x * 256 + threadIdx.x) >> 6;
    const int lane = threadIdx.x & 63;
    const float* srow = sfin + (size_t)wid * 384;
    float u[6] = {0.f, 0.f, 0.f, 0.f, 0.f, 0.f};
    for (int k = lane; k < 384; k += 64) {
        float sv = srow[k];
        #pragma unroll
        for (int j = 0; j < 6; ++j) u[j] += sv * w_bb[k * 6 + j];
    }
    #pragma unroll
    for (int j = 0; j < 6; ++j) {
        #pragma unroll
        for (int o = 32; o > 0; o >>= 1) u[j] += __shfl_xor(u[j], o, 64);
    }
    if (lane == 0) {
        #pragma unroll
        for (int j = 0; j < 6; ++j) u[j] += b_bb[j];
        float bq = u[0], cq = u[1], dq = u[2];
        float inv = rsqrtf(1.f + bq * bq + cq * cq + dq * dq);
        float a = inv, bqn = bq * inv, cqn = cq * inv, dqn = dq * inv;
        float R[9];
        R[0] = a * a + bqn * bqn - cqn * cqn - dqn * dqn;
        R[1] = 2.f * (bqn * cqn - a * dqn);
        R[2] = 2.f * (bqn * dqn + a * cqn);
        R[3] = 2.f * (bqn * cqn + a * dqn);
        R[4] = a * a - bqn * bqn + cqn * cqn - dqn * dqn;
        R[5] = 2.f * (cqn * dqn - a * bqn);
        R[6] = 2.f * (bqn * dqn - a * cqn);
        R[7] = 2.f * (cqn * dqn + a * bqn);
        R[8] = a * a - bqn * bqn - cqn * cqn + dqn * dqn;
        const float* Rt = t_rot + (size_t)wid * 9;
        #pragma unroll
        for (int i2 = 0; i2 < 3; ++i2) {
            #pragma unroll
            for (int k2 = 0; k2 < 3; ++k2) {
                rot_out[(size_t)wid * 9 + i2 * 3 + k2] =
                    Rt[i2 * 3 + 0] * R[0 + k2] + Rt[i2 * 3 + 1] * R[3 + k2] + Rt[i2 * 3 + 2] * R[6 + k2];
            }
            trans_out[(size_t)wid * 3 + i2] =
                Rt[i2 * 3 + 0] * u[3] + Rt[i2 * 3 + 1] * u[4] + Rt[i2 * 3 + 2] * u[5]
                + t_trans[(size_t)wid * 3 + i2];
        }
    }
}

// ---------------------------------------------------------------------------
extern "C" void kernel_launch(void* const* d_in, const int* in_sizes, int n_in,
                              void* d_out, int out_size, void* d_ws, size_t ws_size,
                              hipStream_t stream) {
    const float* s      = (const float*)d_in[0];
    const float* p      = (const float*)d_in[1];
    const float* t_rot  = (const float*)d_in[2];
    const float* t_trans= (const float*)d_in[3];
    const float* mask   = (const float*)d_in[4];
    const float* wq     = (const float*)d_in[5];
    const float* bq     = (const float*)d_in[6];
    const float* wkv    = (const float*)d_in[7];
    const float* bkv    = (const float*)d_in[8];
    const float* wqp    = (const float*)d_in[9];
    const float* bqp    = (const float*)d_in[10];
    const float* wkvp   = (const float*)d_in[11];
    const float* bkvp   = (const float*)d_in[12];
    const float* wb     = (const float*)d_in[13];
    const float* bpb    = (const float*)d_in[14];
    const float* hwts   = (const float*)d_in[15];
    const float* w_out  = (const float*)d_in[16];
    const float* b_out  = (const float*)d_in[17];
    const float* ln1s   = (const float*)d_in[18];
    const float* ln1b   = (const float*)d_in[19];
    const float* wt1    = (const float*)d_in[20];
    const float* bt1    = (const float*)d_in[21];
    const float* wt2    = (const float*)d_in[22];
    const float* bt2    = (const float*)d_in[23];
    const float* wt3    = (const float*)d_in[24];
    const float* bt3    = (const float*)d_in[25];
    const float* ln2s   = (const float*)d_in[26];
    const float* ln2b   = (const float*)d_in[27];
    const float* w_bb   = (const float*)d_in[28];
    const float* b_bb   = (const float*)d_in[29];
    float* out = (float*)d_out;
    float* ws  = (float*)d_ws;

    float* q_o   = ws;                    // 196608
    float* kT2   = q_o   + 196608;        // 196608
    float* vT    = kT2   + 196608;        // 196608
    float* qpl   = vT    + 196608;        // 147456
    float* qpg   = qpl   + 147456;        // 147456
    float* kvpl  = qpg   + 147456;        // 442368
    float* kpT2  = kvpl  + 442368;        // 147456
    float* vptsT = kpT2  + 147456;        // 294912
    float* feats = vptsT + 294912;        // 2162688
    float* s1    = feats + 2162688;       // 393216
    float* g1p   = s1    + 393216;        // 3 x 393216
    float* h1p   = g1p   + 1179648;       // 2 x 393216
    float* h2p   = h1p   + 786432;        // 2 x 393216
    float* s2p   = h2p   + 786432;        // 2 x 393216

    k_proj<<<dim3(32, 9), 256, 0, stream>>>(s, wq, bq, wkv, bkv, wqp, bqp, wkvp, bkvp,
                                            q_o, kT2, vT, qpl, kvpl);
    k_pts<<<1024, 192, 0, stream>>>(qpl, kvpl, t_rot, t_trans, qpg, kpT2, vptsT);
    k_attn<<<1024, 256, 0, stream>>>(q_o, kT2, vT, qpg, kpT2, vptsT, p, wb, bpb,
                                     hwts, mask, t_rot, t_trans, feats);
    // out-proj: split-K 3 x 704
    k_gemm<<<dim3(32, 3, 3), 256, 0, stream>>>(feats, nullptr, nullptr, 2112,
                                               w_out, g1p, 11, 0);
    k_lnsum<<<256, 256, 0, stream>>>(g1p, 3, b_out, s, ln1s, ln1b, s1);
    // t1: split-K 2 x 192
    k_gemm<<<dim3(32, 3, 2), 256, 0, stream>>>(s1, nullptr, nullptr, 384,
                                               wt1, h1p, 3, 0);
    // t2: A = relu(h1p0 + h1p1 + bt1)
    k_gemm<<<dim3(32, 3, 2), 256, 0, stream>>>(h1p, h1p + 393216, bt1, 384,
                                               wt2, h2p, 3, 1);
    // t3: A = relu(h2p0 + h2p1 + bt2)
    k_gemm<<<dim3(32, 3, 2), 256, 0, stream>>>(h2p, h2p + 393216, bt2, 384,
                                               wt3, s2p, 3, 1);
    k_lnsum<<<256, 256, 0, stream>>>(s2p, 2, bt3, s1, ln2s, ln2b, out);
    k_bb<<<256, 256, 0, stream>>>(out, w_bb, b_bb, t_rot, t_trans,
                                  out + 393216, out + 402432);
}